// Round 5
// baseline (338.092 us; speedup 1.0000x reference)
//
#include <hip/hip_runtime.h>
#include <cstddef>

#define DEV static __device__ __forceinline__

typedef float f32x4 __attribute__((ext_vector_type(4)));
typedef __bf16 bf16x8 __attribute__((ext_vector_type(8)));
typedef __bf16 bf16x4v __attribute__((ext_vector_type(4)));
typedef unsigned short u16x8 __attribute__((ext_vector_type(8)));
typedef unsigned short u16x4 __attribute__((ext_vector_type(4)));
typedef _Float16 f16;
typedef _Float16 f16x4 __attribute__((ext_vector_type(4)));

constexpr int BB = 2, LL = 2048, DM = 1024, NH = 16, DK = 64;
constexpr float LOG2E = 1.44269504f;

DEV unsigned short f2bf(float f) {
  unsigned u = __builtin_bit_cast(unsigned, f);
  u += 0x7fffu + ((u >> 16) & 1u);  // RNE
  return (unsigned short)(u >> 16);
}
DEV u16x4 cvt4(f32x4 v) {  // packed f32x4 -> bf16x4
  bf16x4v b = __builtin_convertvector(v, bf16x4v);
  return __builtin_bit_cast(u16x4, b);
}
DEV bf16x8 asbf(u16x8 v) { return __builtin_bit_cast(bf16x8, v); }
DEV f32x4 mfma16(u16x8 a, u16x8 b, f32x4 c) {
  return __builtin_amdgcn_mfma_f32_16x16x32_bf16(asbf(a), asbf(b), c, 0, 0, 0);
}
#if __has_builtin(__builtin_amdgcn_exp2f)
DEV float fexp2(float x) { return __builtin_amdgcn_exp2f(x); }
#else
DEV float fexp2(float x) { return exp2f(x); }
#endif
// async global->LDS, 16B/lane; lds dest wave-uniform base (+lane*16 by HW)
DEV void g2lds16(const void* g, void* l) {
  __builtin_amdgcn_global_load_lds(
      (const __attribute__((address_space(1))) unsigned int*)g,
      (__attribute__((address_space(3))) unsigned int*)l, 16, 0, 0);
}

// ---------------------------------------------------------------------------
// prep_w: transpose+convert 4 weight matrices (1024x1024 fp32, K-major) into
// bf16 W^T[N][K]. grid (32,32,4), block (32,8)
// ---------------------------------------------------------------------------
__global__ __launch_bounds__(256) void prep_w(const float* __restrict__ w0,
                                              const float* __restrict__ w1,
                                              const float* __restrict__ w2,
                                              const float* __restrict__ w3,
                                              unsigned short* __restrict__ wT) {
  __shared__ float tile[32][33];
  int z = blockIdx.z;
  const float* W = (z == 0) ? w0 : (z == 1) ? w1 : (z == 2) ? w2 : w3;
  unsigned short* out = wT + (size_t)z * DM * DM;
  int k0 = blockIdx.y * 32, n0 = blockIdx.x * 32;
  int tx = threadIdx.x, ty = threadIdx.y;
#pragma unroll
  for (int p = 0; p < 4; p++)
    tile[ty + 8 * p][tx] = W[(size_t)(k0 + ty + 8 * p) * DM + n0 + tx];
  __syncthreads();
#pragma unroll
  for (int p = 0; p < 4; p++)
    out[(size_t)(n0 + ty + 8 * p) * DM + k0 + tx] = f2bf(tile[tx][ty + 8 * p]);
}

// ---------------------------------------------------------------------------
// prep_bm: fused f16 bias/mask in exp2 domain: bm = (mask?bias:-1e4)*log2e
// ---------------------------------------------------------------------------
__global__ __launch_bounds__(256) void prep_bm(const int* __restrict__ mask,
                                               const float* __restrict__ bias,
                                               f16* __restrict__ bm) {
  size_t i = ((size_t)blockIdx.x * 256 + threadIdx.x) * 4;
  int4 mk = *(const int4*)(mask + i);
  float4 bs = *(const float4*)(bias + i);
  f16x4 o;
  o[0] = (f16)((mk.x == 0 ? -10000.f : bs.x) * LOG2E);
  o[1] = (f16)((mk.y == 0 ? -10000.f : bs.y) * LOG2E);
  o[2] = (f16)((mk.z == 0 ? -10000.f : bs.z) * LOG2E);
  o[3] = (f16)((mk.w == 0 ? -10000.f : bs.w) * LOG2E);
  *(f16x4*)(bm + i) = o;
}

// ---------------------------------------------------------------------------
// prep_cvt: fp32 -> bf16 for q,k,v activations. grid (2048,3), block 256
// ---------------------------------------------------------------------------
__global__ __launch_bounds__(256) void prep_cvt(const float* __restrict__ s0,
                                                const float* __restrict__ s1,
                                                const float* __restrict__ s2,
                                                unsigned short* __restrict__ dst) {
  int z = blockIdx.y;
  const float* src = (z == 0) ? s0 : (z == 1) ? s1 : s2;
  size_t i = ((size_t)blockIdx.x * 256 + threadIdx.x) * 8;
  float4 a = *(const float4*)(src + i);
  float4 b = *(const float4*)(src + i + 4);
  u16x8 o;
  o[0] = f2bf(a.x); o[1] = f2bf(a.y); o[2] = f2bf(a.z); o[3] = f2bf(a.w);
  o[4] = f2bf(b.x); o[5] = f2bf(b.y); o[6] = f2bf(b.z); o[7] = f2bf(b.w);
  *(u16x8*)(dst + (size_t)z * (size_t)(BB * LL) * DM + i) = o;
}

// ---------------------------------------------------------------------------
// GEMM core: 128x64 block tile, BK=64, 256 thr (4 waves 2x2, wave 64x32),
// global_load_lds coalesced staging into XOR-swizzled LDS, single-buffered
// (m97 discipline). 24 KB LDS -> up to 6 blocks/CU resident.
// ---------------------------------------------------------------------------
template <int KITERS>
DEV void gemm_core(const unsigned short* __restrict__ A,
                   const unsigned short* __restrict__ BT,
                   unsigned short* Al, unsigned short* Bl,
                   int m0, int n0, int k0beg, int t, f32x4 (&acc)[4][2]) {
  int w = t >> 6, lane = t & 63, c = lane & 15, qd = lane >> 4;
  int wm = w >> 1, wn = w & 1;
  int rt = t >> 3, gg = t & 7;
#pragma unroll 1
  for (int kk = 0; kk < KITERS; ++kk) {
    int k0 = k0beg + kk * 64;
    __syncthreads();
#pragma unroll
    for (int r = 0; r < 4; ++r) {
      int row = r * 32 + rt;
      int sc = ((gg ^ (row & 7)) << 3);
      g2lds16(&A[(size_t)(m0 + row) * DM + k0 + sc], &Al[r * 2048 + w * 512]);
    }
#pragma unroll
    for (int r = 0; r < 2; ++r) {
      int row = r * 32 + rt;
      int sc = ((gg ^ (row & 7)) << 3);
      g2lds16(&BT[(size_t)(n0 + row) * DM + k0 + sc], &Bl[r * 2048 + w * 512]);
    }
    __syncthreads();
#pragma unroll
    for (int ks = 0; ks < 2; ++ks) {
      u16x8 af[4], bfr[2];
#pragma unroll
      for (int mt = 0; mt < 4; ++mt)
        af[mt] = *(const u16x8*)&Al[(64 * wm + 16 * mt + c) * 64 +
                                    (((4 * ks + qd) ^ (c & 7)) << 3)];
#pragma unroll
      for (int nt = 0; nt < 2; ++nt)
        bfr[nt] = *(const u16x8*)&Bl[(32 * wn + 16 * nt + c) * 64 +
                                     (((4 * ks + qd) ^ (c & 7)) << 3)];
#pragma unroll
      for (int mt = 0; mt < 4; ++mt)
#pragma unroll
        for (int nt = 0; nt < 2; ++nt)
          acc[mt][nt] = mfma16(af[mt], bfr[nt], acc[mt][nt]);
    }
  }
}

// fused q/k/v projections, bf16 A: grid (16, 32, 3), block 256
__global__ __launch_bounds__(256) void proj_gemm(const unsigned short* __restrict__ qkvb,
                                                 const unsigned short* __restrict__ wT,
                                                 unsigned short* __restrict__ qh,
                                                 unsigned short* __restrict__ kh,
                                                 unsigned short* __restrict__ vT) {
  __shared__ unsigned short Al[128 * 64];  // 16 KiB
  __shared__ unsigned short Bl[64 * 64];   //  8 KiB
  int z = blockIdx.z;
  const unsigned short* A = qkvb + (size_t)z * BB * LL * DM;
  const unsigned short* BT = wT + (size_t)z * DM * DM;
  int t = threadIdx.x, lane = t & 63, c = lane & 15, qd = lane >> 4;
  int w = t >> 6, wm = w >> 1, wn = w & 1;
  int m0 = blockIdx.y * 128, n0 = blockIdx.x * 64;
  f32x4 acc[4][2] = {};
  gemm_core<DM / 64>(A, BT, Al, Bl, m0, n0, 0, t, acc);

  if (z == 2) {  // V: per-head transposed vT[b][h][d][l]
#pragma unroll
    for (int mt = 0; mt < 4; ++mt)
#pragma unroll
      for (int nt = 0; nt < 2; ++nt) {
        int n = n0 + 32 * wn + 16 * nt + c;
        int h = n >> 6, d = n & 63;
        int m = m0 + 64 * wm + 16 * mt + 4 * qd;  // i=0..3 consecutive in l
        int b = m >> 11, l = m & 2047;
        *(u16x4*)&vT[(((size_t)b * NH + h) * DK + d) * LL + l] = cvt4(acc[mt][nt]);
      }
  } else {  // Q/K: head-split [b][h][l][d]; Q carries temperature*log2e
    unsigned short* Ch = z ? kh : qh;
    float scale = z ? 1.0f : 0.125f * LOG2E;
#pragma unroll
    for (int mt = 0; mt < 4; ++mt)
#pragma unroll
      for (int nt = 0; nt < 2; ++nt) {
        int n = n0 + 32 * wn + 16 * nt + c;
        int h = n >> 6, d = n & 63;
#pragma unroll
        for (int i = 0; i < 4; ++i) {
          int m = m0 + 64 * wm + 16 * mt + 4 * qd + i;
          int b = m >> 11, l = m & 2047;
          Ch[(((size_t)b * NH + h) * LL + l) * DK + d] = f2bf(acc[mt][nt][i] * scale);
        }
      }
  }
}

// final fc: split-K=2, fp32 atomics onto zeroed d_out. grid (16, 32, 2)
__global__ __launch_bounds__(256) void fc_gemm(const unsigned short* __restrict__ A,
                                               const unsigned short* __restrict__ BT,
                                               float* __restrict__ C) {
  __shared__ unsigned short Al[128 * 64];
  __shared__ unsigned short Bl[64 * 64];
  int t = threadIdx.x, lane = t & 63, c = lane & 15, qd = lane >> 4;
  int w = t >> 6, wm = w >> 1, wn = w & 1;
  int m0 = blockIdx.y * 128, n0 = blockIdx.x * 64;
  f32x4 acc[4][2] = {};
  gemm_core<8>(A, BT, Al, Bl, m0, n0, blockIdx.z * 512, t, acc);
#pragma unroll
  for (int mt = 0; mt < 4; ++mt)
#pragma unroll
    for (int nt = 0; nt < 2; ++nt) {
      int n = n0 + 32 * wn + 16 * nt + c;
#pragma unroll
      for (int i = 0; i < 4; ++i) {
        int m = m0 + 64 * wm + 16 * mt + 4 * qd + i;
        unsafeAtomicAdd(&C[(size_t)m * DM + n], acc[mt][nt][i]);
      }
    }
}

// ---------------------------------------------------------------------------
// attn: flash-style, 128 q-rows/block (4 waves x 32 q), TK=64, ping-pong
// K/V/bias DMA staging (coalesced global_load_lds; kills the 16-way
// uncoalesced per-lane bias reads). No online max (logits bounded):
// p = exp2(s + bias), li reduced once at the end. LDS 80 KB -> 2 blocks/CU.
// grid (16 x=q-block, 16 y=h, 2 z=b): all heads of (b,q0) on one XCD.
// ---------------------------------------------------------------------------
__global__ __launch_bounds__(256) void attn_kern(const unsigned short* __restrict__ qh,
                                                 const unsigned short* __restrict__ kh,
                                                 const unsigned short* __restrict__ vT,
                                                 const f16* __restrict__ bm,
                                                 unsigned short* __restrict__ O) {
  __shared__ unsigned short Kb[2][4096];    // 16 KiB swizzled [key][d]
  __shared__ unsigned short Vb[2][4096];    // 16 KiB swizzled [d][key]
  __shared__ f16 Bb[2][8192];               // 32 KiB swizzled [q][key]
  __shared__ unsigned short Pq[4][32][64];  // 16 KiB per-wave P^T; Q at start
  unsigned short* Ql = &Pq[0][0][0];        // 128x64 staged Q aliases Pq

  int t = threadIdx.x, w = t >> 6, lane = t & 63, c = lane & 15, qd = lane >> 4;
  int q0 = blockIdx.x * 128, h = blockIdx.y, b = blockIdx.z;
  const unsigned short* Q = qh + (((size_t)b * NH + h) * LL + q0) * DK;
  const unsigned short* K = kh + ((size_t)b * NH + h) * LL * DK;
  const unsigned short* V = vT + ((size_t)b * NH + h) * DK * LL;
  const f16* BM = bm + ((size_t)b * LL + q0) * LL;  // tile rows q0..q0+127
  int rt = t >> 3, gg = t & 7;

  // stage Q (128x64), K/V tile 0, bias tile 0
#pragma unroll
  for (int r = 0; r < 4; ++r) {
    int row = r * 32 + rt;
    int sc = ((gg ^ (row & 7)) << 3);
    g2lds16(&Q[(size_t)row * DK + sc], &Ql[r * 2048 + w * 512]);
    g2lds16(&BM[(size_t)row * LL + sc], &Bb[0][r * 2048 + w * 512]);
  }
#pragma unroll
  for (int r = 0; r < 2; ++r) {
    int row = r * 32 + rt;
    int sc = ((gg ^ (row & 7)) << 3);
    g2lds16(&K[(size_t)row * DK + sc], &Kb[0][r * 2048 + w * 512]);
    g2lds16(&V[(size_t)row * LL + sc], &Vb[0][r * 2048 + w * 512]);
  }
  __syncthreads();
  u16x8 qf[2][2];  // [nt][ks]
#pragma unroll
  for (int nt = 0; nt < 2; ++nt)
#pragma unroll
    for (int ks = 0; ks < 2; ++ks)
      qf[nt][ks] = *(const u16x8*)&Ql[(32 * w + 16 * nt + c) * 64 +
                                      (((4 * ks + qd) ^ (c & 7)) << 3)];
  __syncthreads();  // Ql dead -> Pq reuse race-free

  float li[2] = {0.f, 0.f};
  f32x4 oacc[4][2] = {};  // [dt][nt]

#pragma unroll 1
  for (int it = 0; it < 32; ++it) {
    int cur = it & 1;
    const unsigned short* Kl = Kb[cur];
    const unsigned short* Vt = Vb[cur];
    if (it + 1 < 32) {  // prefetch next K/V/bias tiles (drain at iter-end)
      int nb = cur ^ 1, kt1 = (it + 1) * 64;
#pragma unroll
      for (int r = 0; r < 2; ++r) {
        int row = r * 32 + rt;
        int sc = ((gg ^ (row & 7)) << 3);
        g2lds16(&K[(size_t)(kt1 + row) * DK + sc], &Kb[nb][r * 2048 + w * 512]);
        g2lds16(&V[(size_t)row * LL + kt1 + sc], &Vb[nb][r * 2048 + w * 512]);
      }
#pragma unroll
      for (int r = 0; r < 4; ++r) {
        int row = r * 32 + rt;
        int sc = ((gg ^ (row & 7)) << 3);
        g2lds16(&BM[(size_t)row * LL + kt1 + sc], &Bb[nb][r * 2048 + w * 512]);
      }
    }

    // S^T = K.Q^T : lane holds q-col c (per nt), keys 16mt+4qd+i
    f32x4 s[4][2];
#pragma unroll
    for (int mt = 0; mt < 4; ++mt) {
      int row = 16 * mt + c;
      u16x8 k0f = *(const u16x8*)&Kl[row * 64 + ((qd ^ (c & 7)) << 3)];
      u16x8 k1f = *(const u16x8*)&Kl[row * 64 + (((4 + qd) ^ (c & 7)) << 3)];
#pragma unroll
      for (int nt = 0; nt < 2; ++nt) {
        f32x4 z = {0.f, 0.f, 0.f, 0.f};
        z = mfma16(k0f, qf[nt][0], z);
        s[mt][nt] = mfma16(k1f, qf[nt][1], z);
      }
    }
    // p = exp2(s + bias); bias from swizzled LDS (f16x4, conflict-free)
#pragma unroll
    for (int nt = 0; nt < 2; ++nt) {
      int qrow = (32 * w + 16 * nt + c) * 64;
#pragma unroll
      for (int mt = 0; mt < 4; ++mt) {
        f16x4 b4 = *(const f16x4*)&Bb[cur][qrow +
                                           (((2 * mt + (qd >> 1)) ^ (c & 7)) << 3) +
                                           ((qd & 1) << 2)];
        f32x4 p;
#pragma unroll
        for (int i = 0; i < 4; ++i) {
          p[i] = fexp2(s[mt][nt][i] + (float)b4[i]);
          li[nt] += p[i];
        }
        int off = (((2 * mt + (qd >> 1)) ^ (c & 7)) << 3) + ((qd & 1) << 2);
        *(u16x4*)&Pq[w][16 * nt + c][off] = cvt4(p);  // wave-private
      }
    }
    // O^T += V^T.P^T
    u16x8 pf[2][2];
#pragma unroll
    for (int nt = 0; nt < 2; ++nt)
#pragma unroll
      for (int ks = 0; ks < 2; ++ks)
        pf[nt][ks] =
            *(const u16x8*)&Pq[w][16 * nt + c][(((4 * ks + qd) ^ (c & 7)) << 3)];
#pragma unroll
    for (int dt = 0; dt < 4; ++dt) {
      int row = 16 * dt + c;
      u16x8 v0f = *(const u16x8*)&Vt[row * 64 + ((qd ^ (c & 7)) << 3)];
      u16x8 v1f = *(const u16x8*)&Vt[row * 64 + (((4 + qd) ^ (c & 7)) << 3)];
#pragma unroll
      for (int nt = 0; nt < 2; ++nt) {
        oacc[dt][nt] = mfma16(v0f, pf[nt][0], oacc[dt][nt]);
        oacc[dt][nt] = mfma16(v1f, pf[nt][1], oacc[dt][nt]);
      }
    }
    __syncthreads();  // drains prefetch DMA (in flight during compute)
  }

  // epilogue: reduce li across qd groups, store O[b][q][h*64+d] bf16
#pragma unroll
  for (int nt = 0; nt < 2; ++nt) {
    float l = li[nt];
    l += __shfl_xor(l, 16);
    l += __shfl_xor(l, 32);
    float rl = 1.f / l;
    size_t orow = ((size_t)b * LL + q0 + 32 * w + 16 * nt + c) * DM + h * DK;
#pragma unroll
    for (int dt = 0; dt < 4; ++dt)
      *(u16x4*)&O[orow + 16 * dt + 4 * qd] = cvt4(oacc[dt][nt] * rl);
  }
}

// ---------------------------------------------------------------------------
extern "C" void kernel_launch(void* const* d_in, const int* in_sizes, int n_in,
                              void* d_out, int out_size, void* d_ws, size_t ws_size,
                              hipStream_t stream) {
  (void)in_sizes; (void)n_in; (void)ws_size;
  const float* q = (const float*)d_in[0];
  const float* k = (const float*)d_in[1];
  const float* v = (const float*)d_in[2];
  const int* mask = (const int*)d_in[3];
  const float* bias = (const float*)d_in[4];
  const float* w_qs = (const float*)d_in[5];
  const float* w_ks = (const float*)d_in[6];
  const float* w_vs = (const float*)d_in[7];
  const float* w_fc = (const float*)d_in[8];

  char* ws = (char*)d_ws;
  const size_t MB = 1024 * 1024;
  unsigned short* wT = (unsigned short*)(ws);              // [0,8M)
  f16* bmw = (f16*)(ws + 8 * MB);                          // [8,24M)
  unsigned short* qkvb = (unsigned short*)(ws + 24 * MB);  // [24,48M)
  unsigned short* qh = (unsigned short*)(ws + 48 * MB);    // [48,56M)
  unsigned short* kh = (unsigned short*)(ws + 56 * MB);    // [56,64M)
  unsigned short* vhT = (unsigned short*)(ws + 64 * MB);   // [64,72M)
  unsigned short* Obuf = (unsigned short*)(ws + 72 * MB);  // [72,80M)

  prep_w<<<dim3(32, 32, 4), dim3(32, 8, 1), 0, stream>>>(w_qs, w_ks, w_vs, w_fc, wT);
  prep_bm<<<dim3(8192), dim3(256), 0, stream>>>(mask, bias, bmw);
  prep_cvt<<<dim3(2048, 3), dim3(256), 0, stream>>>(q, k, v, qkvb);
  proj_gemm<<<dim3(16, 32, 3), 256, 0, stream>>>(qkvb, wT, qh, kh, vhT);
  attn_kern<<<dim3(16, 16, 2), 256, 0, stream>>>(qh, kh, vhT, bmw, Obuf);
  hipMemsetAsync(d_out, 0, (size_t)out_size * sizeof(float), stream);
  fc_gemm<<<dim3(16, 32, 2), 256, 0, stream>>>(Obuf, wT + (size_t)3 * DM * DM,
                                               (float*)d_out);
}

// Round 6
// 313.814 us; speedup vs baseline: 1.0774x; 1.0774x over previous
//
#include <hip/hip_runtime.h>
#include <cstddef>

#define DEV static __device__ __forceinline__

typedef float f32x4 __attribute__((ext_vector_type(4)));
typedef __bf16 bf16x8 __attribute__((ext_vector_type(8)));
typedef __bf16 bf16x4v __attribute__((ext_vector_type(4)));
typedef unsigned short u16x8 __attribute__((ext_vector_type(8)));
typedef unsigned short u16x4 __attribute__((ext_vector_type(4)));
typedef _Float16 f16;
typedef _Float16 f16x4 __attribute__((ext_vector_type(4)));

constexpr int BB = 2, LL = 2048, DM = 1024, NH = 16, DK = 64;
constexpr float LOG2E = 1.44269504f;

DEV unsigned short f2bf(float f) {
  unsigned u = __builtin_bit_cast(unsigned, f);
  u += 0x7fffu + ((u >> 16) & 1u);  // RNE
  return (unsigned short)(u >> 16);
}
DEV u16x4 cvt4(f32x4 v) {  // packed f32x4 -> bf16x4
  bf16x4v b = __builtin_convertvector(v, bf16x4v);
  return __builtin_bit_cast(u16x4, b);
}
DEV bf16x8 asbf(u16x8 v) { return __builtin_bit_cast(bf16x8, v); }
DEV f32x4 mfma16(u16x8 a, u16x8 b, f32x4 c) {
  return __builtin_amdgcn_mfma_f32_16x16x32_bf16(asbf(a), asbf(b), c, 0, 0, 0);
}
#if __has_builtin(__builtin_amdgcn_exp2f)
DEV float fexp2(float x) { return __builtin_amdgcn_exp2f(x); }
#else
DEV float fexp2(float x) { return exp2f(x); }
#endif
// async global->LDS, 16B/lane; lds dest wave-uniform base (+lane*16 by HW)
DEV void g2lds16(const void* g, void* l) {
  __builtin_amdgcn_global_load_lds(
      (const __attribute__((address_space(1))) unsigned int*)g,
      (__attribute__((address_space(3))) unsigned int*)l, 16, 0, 0);
}

// ---------------------------------------------------------------------------
// prep_w: transpose+convert 4 weight matrices (1024x1024 fp32, K-major) into
// bf16 W^T[N][K]. grid (32,32,4), block (32,8)
// ---------------------------------------------------------------------------
__global__ __launch_bounds__(256) void prep_w(const float* __restrict__ w0,
                                              const float* __restrict__ w1,
                                              const float* __restrict__ w2,
                                              const float* __restrict__ w3,
                                              unsigned short* __restrict__ wT) {
  __shared__ float tile[32][33];
  int z = blockIdx.z;
  const float* W = (z == 0) ? w0 : (z == 1) ? w1 : (z == 2) ? w2 : w3;
  unsigned short* out = wT + (size_t)z * DM * DM;
  int k0 = blockIdx.y * 32, n0 = blockIdx.x * 32;
  int tx = threadIdx.x, ty = threadIdx.y;
#pragma unroll
  for (int p = 0; p < 4; p++)
    tile[ty + 8 * p][tx] = W[(size_t)(k0 + ty + 8 * p) * DM + n0 + tx];
  __syncthreads();
#pragma unroll
  for (int p = 0; p < 4; p++)
    out[(size_t)(n0 + ty + 8 * p) * DM + k0 + tx] = f2bf(tile[tx][ty + 8 * p]);
}

// ---------------------------------------------------------------------------
// prep_bm: fused f16 bias/mask in exp2 domain: bm = (mask?bias:-1e4)*log2e
// ---------------------------------------------------------------------------
__global__ __launch_bounds__(256) void prep_bm(const int* __restrict__ mask,
                                               const float* __restrict__ bias,
                                               f16* __restrict__ bm) {
  size_t i = ((size_t)blockIdx.x * 256 + threadIdx.x) * 4;
  int4 mk = *(const int4*)(mask + i);
  float4 bs = *(const float4*)(bias + i);
  f16x4 o;
  o[0] = (f16)((mk.x == 0 ? -10000.f : bs.x) * LOG2E);
  o[1] = (f16)((mk.y == 0 ? -10000.f : bs.y) * LOG2E);
  o[2] = (f16)((mk.z == 0 ? -10000.f : bs.z) * LOG2E);
  o[3] = (f16)((mk.w == 0 ? -10000.f : bs.w) * LOG2E);
  *(f16x4*)(bm + i) = o;
}

// ---------------------------------------------------------------------------
// prep_cvt: fp32 -> bf16 for q,k,v activations. grid (2048,3), block 256
// ---------------------------------------------------------------------------
__global__ __launch_bounds__(256) void prep_cvt(const float* __restrict__ s0,
                                                const float* __restrict__ s1,
                                                const float* __restrict__ s2,
                                                unsigned short* __restrict__ dst) {
  int z = blockIdx.y;
  const float* src = (z == 0) ? s0 : (z == 1) ? s1 : s2;
  size_t i = ((size_t)blockIdx.x * 256 + threadIdx.x) * 8;
  float4 a = *(const float4*)(src + i);
  float4 b = *(const float4*)(src + i + 4);
  u16x8 o;
  o[0] = f2bf(a.x); o[1] = f2bf(a.y); o[2] = f2bf(a.z); o[3] = f2bf(a.w);
  o[4] = f2bf(b.x); o[5] = f2bf(b.y); o[6] = f2bf(b.z); o[7] = f2bf(b.w);
  *(u16x8*)(dst + (size_t)z * (size_t)(BB * LL) * DM + i) = o;
}

// ---------------------------------------------------------------------------
// GEMM core, AITER-style VGPR-path pipeline: 128x128 tile, BK=64, 256 thr
// (4 waves 2x2, wave 64x64 -> 32 MFMA : 16 ds_read per iter).
// buffer_load -> VGPR -> ds_write with double-buffered LDS and ONE barrier
// per iter: loads for k+1 issue at iter top; the vmcnt wait lands at the
// ds_write AFTER the MFMA block (~600 cyc later), so L2-hit latency is
// hidden by compute instead of drained at the barrier (the m97 stall).
// Swizzle applied on the GLOBAL address side: lane t loads col-group
// (t&7)^(row&7) and writes LDS linearly -> coalesced loads, conflict-free
// b128 frag reads, zero extra VALU.
// ---------------------------------------------------------------------------
template <int KITERS>
DEV void gemm_core(const unsigned short* __restrict__ A,
                   const unsigned short* __restrict__ BT,
                   unsigned short (*Al)[128 * 64], unsigned short (*Bl)[128 * 64],
                   int m0, int n0, int k0beg, int t, f32x4 (&acc)[4][4]) {
  int lane = t & 63, c = lane & 15, qd = lane >> 4;
  int w = t >> 6, wm = w >> 1, wn = w & 1;
  int r0 = t >> 3;                    // 0..31; rows r0+32p keep same low 3 bits
  int gsw = (t & 7) ^ (r0 & 7);       // swizzled col-group for this thread
  u16x8 ar[4], br[4];

  auto load_tile = [&](int k0) {
#pragma unroll
    for (int p = 0; p < 4; ++p) {
      ar[p] = *(const u16x8*)&A[(size_t)(m0 + 32 * p + r0) * DM + k0 + 8 * gsw];
      br[p] = *(const u16x8*)&BT[(size_t)(n0 + 32 * p + r0) * DM + k0 + 8 * gsw];
    }
  };
  auto store_tile = [&](int buf) {
#pragma unroll
    for (int p = 0; p < 4; ++p) {  // LDS-linear: addr = row*64 + ((g^r7)<<3)
      *(u16x8*)&Al[buf][p * 2048 + t * 8] = ar[p];
      *(u16x8*)&Bl[buf][p * 2048 + t * 8] = br[p];
    }
  };
  auto compute = [&](int buf) {
#pragma unroll
    for (int ks = 0; ks < 2; ++ks) {
      u16x8 af[4], bfr[4];
#pragma unroll
      for (int mt = 0; mt < 4; ++mt)
        af[mt] = *(const u16x8*)&Al[buf][(64 * wm + 16 * mt + c) * 64 +
                                         (((4 * ks + qd) ^ (c & 7)) << 3)];
#pragma unroll
      for (int nt = 0; nt < 4; ++nt)
        bfr[nt] = *(const u16x8*)&Bl[buf][(64 * wn + 16 * nt + c) * 64 +
                                          (((4 * ks + qd) ^ (c & 7)) << 3)];
#pragma unroll
      for (int mt = 0; mt < 4; ++mt)
#pragma unroll
        for (int nt = 0; nt < 4; ++nt)
          acc[mt][nt] = mfma16(af[mt], bfr[nt], acc[mt][nt]);
    }
  };

  load_tile(k0beg);
  store_tile(0);
  __syncthreads();
#pragma unroll 1
  for (int kk = 0; kk < KITERS; ++kk) {
    if (kk + 1 < KITERS) load_tile(k0beg + (kk + 1) * 64);  // in flight now
    compute(kk & 1);
    if (kk + 1 < KITERS) store_tile((kk + 1) & 1);  // vm-wait lands here
    __syncthreads();
  }
}

// fused q/k/v projections: grid (8, 32, 3), block 256
__global__ __launch_bounds__(256) void proj_gemm(const unsigned short* __restrict__ qkvb,
                                                 const unsigned short* __restrict__ wT,
                                                 unsigned short* __restrict__ qh,
                                                 unsigned short* __restrict__ kh,
                                                 unsigned short* __restrict__ vT) {
  __shared__ unsigned short Al[2][128 * 64];  // 32 KiB
  __shared__ unsigned short Bl[2][128 * 64];  // 32 KiB
  int z = blockIdx.z;
  const unsigned short* A = qkvb + (size_t)z * BB * LL * DM;
  const unsigned short* BT = wT + (size_t)z * DM * DM;
  int t = threadIdx.x, lane = t & 63, c = lane & 15, qd = lane >> 4;
  int w = t >> 6, wm = w >> 1, wn = w & 1;
  int m0 = blockIdx.y * 128, n0 = blockIdx.x * 128;
  f32x4 acc[4][4] = {};
  gemm_core<DM / 64>(A, BT, Al, Bl, m0, n0, 0, t, acc);

  if (z == 2) {  // V: per-head transposed vT[b][h][d][l]
#pragma unroll
    for (int mt = 0; mt < 4; ++mt)
#pragma unroll
      for (int nt = 0; nt < 4; ++nt) {
        int n = n0 + 64 * wn + 16 * nt + c;
        int h = n >> 6, d = n & 63;
        int m = m0 + 64 * wm + 16 * mt + 4 * qd;  // i=0..3 consecutive in l
        int b = m >> 11, l = m & 2047;
        *(u16x4*)&vT[(((size_t)b * NH + h) * DK + d) * LL + l] = cvt4(acc[mt][nt]);
      }
  } else {  // Q/K: head-split [b][h][l][d]; Q carries temperature*log2e
    unsigned short* Ch = z ? kh : qh;
    float scale = z ? 1.0f : 0.125f * LOG2E;
#pragma unroll
    for (int mt = 0; mt < 4; ++mt)
#pragma unroll
      for (int nt = 0; nt < 4; ++nt) {
        int n = n0 + 64 * wn + 16 * nt + c;
        int h = n >> 6, d = n & 63;
#pragma unroll
        for (int i = 0; i < 4; ++i) {
          int m = m0 + 64 * wm + 16 * mt + 4 * qd + i;
          int b = m >> 11, l = m & 2047;
          Ch[(((size_t)b * NH + h) * LL + l) * DK + d] = f2bf(acc[mt][nt][i] * scale);
        }
      }
  }
}

// final fc: split-K=2, fp32 atomics onto zeroed d_out. grid (8, 32, 2)
__global__ __launch_bounds__(256) void fc_gemm(const unsigned short* __restrict__ A,
                                               const unsigned short* __restrict__ BT,
                                               float* __restrict__ C) {
  __shared__ unsigned short Al[2][128 * 64];
  __shared__ unsigned short Bl[2][128 * 64];
  int t = threadIdx.x, lane = t & 63, c = lane & 15, qd = lane >> 4;
  int w = t >> 6, wm = w >> 1, wn = w & 1;
  int m0 = blockIdx.y * 128, n0 = blockIdx.x * 128;
  f32x4 acc[4][4] = {};
  gemm_core<8>(A, BT, Al, Bl, m0, n0, blockIdx.z * 512, t, acc);
#pragma unroll
  for (int mt = 0; mt < 4; ++mt)
#pragma unroll
    for (int nt = 0; nt < 4; ++nt) {
      int n = n0 + 64 * wn + 16 * nt + c;
#pragma unroll
      for (int i = 0; i < 4; ++i) {
        int m = m0 + 64 * wm + 16 * mt + 4 * qd + i;
        unsafeAtomicAdd(&C[(size_t)m * DM + n], acc[mt][nt][i]);
      }
    }
}

// ---------------------------------------------------------------------------
// attn: flash-style, 128 q-rows/block (4 waves x 32 q), TK=64, ping-pong
// K/V/bias DMA staging (coalesced global_load_lds). No online max (logits
// bounded): p = exp2(s + bias), li reduced once at the end. LDS 80 KB ->
// 2 blocks/CU. grid (16 x=q-block, 16 y=h, 2 z=b).
// ---------------------------------------------------------------------------
__global__ __launch_bounds__(256) void attn_kern(const unsigned short* __restrict__ qh,
                                                 const unsigned short* __restrict__ kh,
                                                 const unsigned short* __restrict__ vT,
                                                 const f16* __restrict__ bm,
                                                 unsigned short* __restrict__ O) {
  __shared__ unsigned short Kb[2][4096];    // 16 KiB swizzled [key][d]
  __shared__ unsigned short Vb[2][4096];    // 16 KiB swizzled [d][key]
  __shared__ f16 Bb[2][8192];               // 32 KiB swizzled [q][key]
  __shared__ unsigned short Pq[4][32][64];  // 16 KiB per-wave P^T; Q at start
  unsigned short* Ql = &Pq[0][0][0];        // 128x64 staged Q aliases Pq

  int t = threadIdx.x, w = t >> 6, lane = t & 63, c = lane & 15, qd = lane >> 4;
  int q0 = blockIdx.x * 128, h = blockIdx.y, b = blockIdx.z;
  const unsigned short* Q = qh + (((size_t)b * NH + h) * LL + q0) * DK;
  const unsigned short* K = kh + ((size_t)b * NH + h) * LL * DK;
  const unsigned short* V = vT + ((size_t)b * NH + h) * DK * LL;
  const f16* BM = bm + ((size_t)b * LL + q0) * LL;  // tile rows q0..q0+127
  int rt = t >> 3, gg = t & 7;

  // stage Q (128x64), K/V tile 0, bias tile 0
#pragma unroll
  for (int r = 0; r < 4; ++r) {
    int row = r * 32 + rt;
    int sc = ((gg ^ (row & 7)) << 3);
    g2lds16(&Q[(size_t)row * DK + sc], &Ql[r * 2048 + w * 512]);
    g2lds16(&BM[(size_t)row * LL + sc], &Bb[0][r * 2048 + w * 512]);
  }
#pragma unroll
  for (int r = 0; r < 2; ++r) {
    int row = r * 32 + rt;
    int sc = ((gg ^ (row & 7)) << 3);
    g2lds16(&K[(size_t)row * DK + sc], &Kb[0][r * 2048 + w * 512]);
    g2lds16(&V[(size_t)row * LL + sc], &Vb[0][r * 2048 + w * 512]);
  }
  __syncthreads();
  u16x8 qf[2][2];  // [nt][ks]
#pragma unroll
  for (int nt = 0; nt < 2; ++nt)
#pragma unroll
    for (int ks = 0; ks < 2; ++ks)
      qf[nt][ks] = *(const u16x8*)&Ql[(32 * w + 16 * nt + c) * 64 +
                                      (((4 * ks + qd) ^ (c & 7)) << 3)];
  __syncthreads();  // Ql dead -> Pq reuse race-free

  float li[2] = {0.f, 0.f};
  f32x4 oacc[4][2] = {};  // [dt][nt]

#pragma unroll 1
  for (int it = 0; it < 32; ++it) {
    int cur = it & 1;
    const unsigned short* Kl = Kb[cur];
    const unsigned short* Vt = Vb[cur];
    if (it + 1 < 32) {  // prefetch next K/V/bias tiles (drain at iter-end)
      int nb = cur ^ 1, kt1 = (it + 1) * 64;
#pragma unroll
      for (int r = 0; r < 2; ++r) {
        int row = r * 32 + rt;
        int sc = ((gg ^ (row & 7)) << 3);
        g2lds16(&K[(size_t)(kt1 + row) * DK + sc], &Kb[nb][r * 2048 + w * 512]);
        g2lds16(&V[(size_t)row * LL + kt1 + sc], &Vb[nb][r * 2048 + w * 512]);
      }
#pragma unroll
      for (int r = 0; r < 4; ++r) {
        int row = r * 32 + rt;
        int sc = ((gg ^ (row & 7)) << 3);
        g2lds16(&BM[(size_t)row * LL + kt1 + sc], &Bb[nb][r * 2048 + w * 512]);
      }
    }

    // S^T = K.Q^T : lane holds q-col c (per nt), keys 16mt+4qd+i
    f32x4 s[4][2];
#pragma unroll
    for (int mt = 0; mt < 4; ++mt) {
      int row = 16 * mt + c;
      u16x8 k0f = *(const u16x8*)&Kl[row * 64 + ((qd ^ (c & 7)) << 3)];
      u16x8 k1f = *(const u16x8*)&Kl[row * 64 + (((4 + qd) ^ (c & 7)) << 3)];
#pragma unroll
      for (int nt = 0; nt < 2; ++nt) {
        f32x4 z = {0.f, 0.f, 0.f, 0.f};
        z = mfma16(k0f, qf[nt][0], z);
        s[mt][nt] = mfma16(k1f, qf[nt][1], z);
      }
    }
    // p = exp2(s + bias); bias from swizzled LDS (f16x4, conflict-free)
#pragma unroll
    for (int nt = 0; nt < 2; ++nt) {
      int qrow = (32 * w + 16 * nt + c) * 64;
#pragma unroll
      for (int mt = 0; mt < 4; ++mt) {
        f16x4 b4 = *(const f16x4*)&Bb[cur][qrow +
                                           (((2 * mt + (qd >> 1)) ^ (c & 7)) << 3) +
                                           ((qd & 1) << 2)];
        f32x4 p;
#pragma unroll
        for (int i = 0; i < 4; ++i) {
          p[i] = fexp2(s[mt][nt][i] + (float)b4[i]);
          li[nt] += p[i];
        }
        int off = (((2 * mt + (qd >> 1)) ^ (c & 7)) << 3) + ((qd & 1) << 2);
        *(u16x4*)&Pq[w][16 * nt + c][off] = cvt4(p);  // wave-private
      }
    }
    // O^T += V^T.P^T
    u16x8 pf[2][2];
#pragma unroll
    for (int nt = 0; nt < 2; ++nt)
#pragma unroll
      for (int ks = 0; ks < 2; ++ks)
        pf[nt][ks] =
            *(const u16x8*)&Pq[w][16 * nt + c][(((4 * ks + qd) ^ (c & 7)) << 3)];
#pragma unroll
    for (int dt = 0; dt < 4; ++dt) {
      int row = 16 * dt + c;
      u16x8 v0f = *(const u16x8*)&Vt[row * 64 + ((qd ^ (c & 7)) << 3)];
      u16x8 v1f = *(const u16x8*)&Vt[row * 64 + (((4 + qd) ^ (c & 7)) << 3)];
#pragma unroll
      for (int nt = 0; nt < 2; ++nt) {
        oacc[dt][nt] = mfma16(v0f, pf[nt][0], oacc[dt][nt]);
        oacc[dt][nt] = mfma16(v1f, pf[nt][1], oacc[dt][nt]);
      }
    }
    __syncthreads();  // drains prefetch DMA (in flight during compute)
  }

  // epilogue: reduce li across qd groups, store O[b][q][h*64+d] bf16
#pragma unroll
  for (int nt = 0; nt < 2; ++nt) {
    float l = li[nt];
    l += __shfl_xor(l, 16);
    l += __shfl_xor(l, 32);
    float rl = 1.f / l;
    size_t orow = ((size_t)b * LL + q0 + 32 * w + 16 * nt + c) * DM + h * DK;
#pragma unroll
    for (int dt = 0; dt < 4; ++dt)
      *(u16x4*)&O[orow + 16 * dt + 4 * qd] = cvt4(oacc[dt][nt] * rl);
  }
}

// ---------------------------------------------------------------------------
extern "C" void kernel_launch(void* const* d_in, const int* in_sizes, int n_in,
                              void* d_out, int out_size, void* d_ws, size_t ws_size,
                              hipStream_t stream) {
  (void)in_sizes; (void)n_in; (void)ws_size;
  const float* q = (const float*)d_in[0];
  const float* k = (const float*)d_in[1];
  const float* v = (const float*)d_in[2];
  const int* mask = (const int*)d_in[3];
  const float* bias = (const float*)d_in[4];
  const float* w_qs = (const float*)d_in[5];
  const float* w_ks = (const float*)d_in[6];
  const float* w_vs = (const float*)d_in[7];
  const float* w_fc = (const float*)d_in[8];

  char* ws = (char*)d_ws;
  const size_t MB = 1024 * 1024;
  unsigned short* wT = (unsigned short*)(ws);              // [0,8M)
  f16* bmw = (f16*)(ws + 8 * MB);                          // [8,24M)
  unsigned short* qkvb = (unsigned short*)(ws + 24 * MB);  // [24,48M)
  unsigned short* qh = (unsigned short*)(ws + 48 * MB);    // [48,56M)
  unsigned short* kh = (unsigned short*)(ws + 56 * MB);    // [56,64M)
  unsigned short* vhT = (unsigned short*)(ws + 64 * MB);   // [64,72M)
  unsigned short* Obuf = (unsigned short*)(ws + 72 * MB);  // [72,80M)

  prep_w<<<dim3(32, 32, 4), dim3(32, 8, 1), 0, stream>>>(w_qs, w_ks, w_vs, w_fc, wT);
  prep_bm<<<dim3(8192), dim3(256), 0, stream>>>(mask, bias, bmw);
  prep_cvt<<<dim3(2048, 3), dim3(256), 0, stream>>>(q, k, v, qkvb);
  proj_gemm<<<dim3(8, 32, 3), 256, 0, stream>>>(qkvb, wT, qh, kh, vhT);
  attn_kern<<<dim3(16, 16, 2), 256, 0, stream>>>(qh, kh, vhT, bmw, Obuf);
  hipMemsetAsync(d_out, 0, (size_t)out_size * sizeof(float), stream);
  fc_gemm<<<dim3(8, 32, 2), 256, 0, stream>>>(Obuf, wT + (size_t)3 * DM * DM,
                                              (float*)d_out);
}